// Round 1
// baseline (3648.706 us; speedup 1.0000x reference)
//
#include <hip/hip_runtime.h>
#include <math.h>

// Problem constants
#define B_SZ 512
#define T_SZ 128
#define D_SZ 128
#define H_SZ 256
#define K_SZ 49
#define L_SZ 7
#define E_SZ 512   // 2H
#define G_SZ 1024  // 4H
#define NP_SZ 2048 // 2 * 4H (both directions, permuted gate space)
#define KK_SZ 384  // H + D (fused recurrent + input K dim)

__device__ __forceinline__ float sigm(float x) { return 1.0f / (1.0f + expf(-x)); }

// ---------------------------------------------------------------------------
// Weight permutation: Wp[n'][k], n' = dir*1024 + j*4 + g, k<256 -> w_hh, else w_ih
// ---------------------------------------------------------------------------
__global__ __launch_bounds__(256) void prep_kernel(
    const float* __restrict__ w_ih_f, const float* __restrict__ w_hh_f,
    const float* __restrict__ b_f, const float* __restrict__ w_ih_b,
    const float* __restrict__ w_hh_b, const float* __restrict__ b_b,
    float* __restrict__ Wp, float* __restrict__ bp)
{
    int idx = blockIdx.x * 256 + threadIdx.x;
    if (idx >= NP_SZ * KK_SZ) return;
    int np = idx / KK_SZ, k = idx % KK_SZ;
    int dir = np >> 10;
    int loc = np & 1023;
    int j = loc >> 2, g = loc & 3;
    int row = g * H_SZ + j;           // original row in [4H, *] weight
    const float* w_ih = dir ? w_ih_b : w_ih_f;
    const float* w_hh = dir ? w_hh_b : w_hh_f;
    float v = (k < H_SZ) ? w_hh[row * H_SZ + k] : w_ih[row * D_SZ + (k - H_SZ)];
    Wp[idx] = v;
    if (k == 0) bp[np] = (dir ? b_b : b_f)[row];
}

// ---------------------------------------------------------------------------
// One LSTM timestep, both directions fused.
// gates[b, n'] = sum_k A[b,k] * Wp[n',k],  A = [h_prev | x_t]
// Epilogue applies LSTM cell, updates cstate, writes h into hist[t][b][dir*256+j]
// Grid: 256 blocks (8 b-tiles x 32 n'-tiles), 256 threads, 64x64 tile, 4x4 micro
// ---------------------------------------------------------------------------
__global__ __launch_bounds__(256) void lstm_step(
    int s, const float* __restrict__ x, const float* __restrict__ Wp,
    const float* __restrict__ bp, float* __restrict__ hist,
    float* __restrict__ cstate)
{
    int bt = blockIdx.x >> 5;   // 0..7
    int nt = blockIdx.x & 31;   // 0..31
    int b0 = bt * 64;
    int n0 = nt * 64;
    int dir = n0 >> 10;
    int t_out, t_prev, t_x;
    if (dir == 0) { t_out = s;        t_prev = s - 1;      t_x = s; }
    else          { t_out = 127 - s;  t_prev = 128 - s;    t_x = 127 - s; }

    int tid = threadIdx.x;
    int tx = tid & 15, ty = tid >> 4;
    int lm = tid >> 2;            // 0..63
    int lk4 = (tid & 3) * 4;      // 0,4,8,12

    __shared__ float As[16][68];
    __shared__ float Bs[16][68];
    float acc[4][4] = {};

    for (int k0 = 0; k0 < KK_SZ; k0 += 16) {
        int k = k0 + lk4;
        int b = b0 + lm;
        float4 av, bv;
        if (k < H_SZ) {
            if (s == 0) {
                av = make_float4(0.f, 0.f, 0.f, 0.f);
            } else {
                const float* p = hist + (((size_t)t_prev * B_SZ + b) * E_SZ) + dir * H_SZ + k;
                av = *reinterpret_cast<const float4*>(p);
            }
        } else {
            const float* p = x + (((size_t)b * T_SZ) + t_x) * D_SZ + (k - H_SZ);
            av = *reinterpret_cast<const float4*>(p);
        }
        bv = *reinterpret_cast<const float4*>(Wp + ((size_t)(n0 + lm)) * KK_SZ + k);

        __syncthreads();
        As[lk4 + 0][lm] = av.x; As[lk4 + 1][lm] = av.y;
        As[lk4 + 2][lm] = av.z; As[lk4 + 3][lm] = av.w;
        Bs[lk4 + 0][lm] = bv.x; Bs[lk4 + 1][lm] = bv.y;
        Bs[lk4 + 2][lm] = bv.z; Bs[lk4 + 3][lm] = bv.w;
        __syncthreads();

        #pragma unroll
        for (int kk = 0; kk < 16; ++kk) {
            float a[4], w[4];
            #pragma unroll
            for (int r = 0; r < 4; ++r) a[r] = As[kk][ty * 4 + r];
            #pragma unroll
            for (int c = 0; c < 4; ++c) w[c] = Bs[kk][tx * 4 + c];
            #pragma unroll
            for (int r = 0; r < 4; ++r)
                #pragma unroll
                for (int c = 0; c < 4; ++c)
                    acc[r][c] += a[r] * w[c];
        }
    }

    // Epilogue: each thread owns 4 batch rows x 1 h-cell (4 gates)
    int j = ((n0 & 1023) >> 2) + tx;      // h index within direction
    float bias[4];
    #pragma unroll
    for (int c = 0; c < 4; ++c) bias[c] = bp[n0 + tx * 4 + c];
    #pragma unroll
    for (int r = 0; r < 4; ++r) {
        int b = b0 + ty * 4 + r;
        float iv = sigm(acc[r][0] + bias[0]);
        float fv = sigm(acc[r][1] + bias[1]);
        float gv = tanhf(acc[r][2] + bias[2]);
        float ov = sigm(acc[r][3] + bias[3]);
        size_t cidx = ((size_t)dir * B_SZ + b) * H_SZ + j;
        float cold = (s == 0) ? 0.f : cstate[cidx];
        float cnew = fv * cold + iv * gv;
        cstate[cidx] = cnew;
        hist[(((size_t)t_out * B_SZ) + b) * E_SZ + dir * H_SZ + j] = ov * tanhf(cnew);
    }
}

// ---------------------------------------------------------------------------
// Attention tanh layer + aw2 dot, fused:
// scores[r] += sum_h_in_tile aw2[h] * tanh(ab1[h] + sum_e hist[r][e]*aw1[h][e])
// r = t*512 + b (natural hist row order). Rows 65536, cols 256, K=512.
// Grid: 4096 blocks (1024 row-tiles x 4 col-tiles)
// ---------------------------------------------------------------------------
__global__ __launch_bounds__(256) void attn_gemm(
    const float* __restrict__ hist, const float* __restrict__ aw1,
    const float* __restrict__ ab1, const float* __restrict__ aw2,
    float* __restrict__ scores)
{
    int rt = blockIdx.x >> 2;
    int ct = blockIdx.x & 3;
    int r0 = rt * 64, h0 = ct * 64;

    int tid = threadIdx.x;
    int tx = tid & 15, ty = tid >> 4;
    int lm = tid >> 2;
    int lk4 = (tid & 3) * 4;

    __shared__ float As[16][68];
    __shared__ float Bs[16][68];
    float acc[4][4] = {};

    for (int k0 = 0; k0 < E_SZ; k0 += 16) {
        float4 av = *reinterpret_cast<const float4*>(
            hist + ((size_t)(r0 + lm)) * E_SZ + k0 + lk4);
        float4 bv = *reinterpret_cast<const float4*>(
            aw1 + ((size_t)(h0 + lm)) * E_SZ + k0 + lk4);
        __syncthreads();
        As[lk4 + 0][lm] = av.x; As[lk4 + 1][lm] = av.y;
        As[lk4 + 2][lm] = av.z; As[lk4 + 3][lm] = av.w;
        Bs[lk4 + 0][lm] = bv.x; Bs[lk4 + 1][lm] = bv.y;
        Bs[lk4 + 2][lm] = bv.z; Bs[lk4 + 3][lm] = bv.w;
        __syncthreads();
        #pragma unroll
        for (int kk = 0; kk < 16; ++kk) {
            float a[4], w[4];
            #pragma unroll
            for (int r = 0; r < 4; ++r) a[r] = As[kk][ty * 4 + r];
            #pragma unroll
            for (int c = 0; c < 4; ++c) w[c] = Bs[kk][tx * 4 + c];
            #pragma unroll
            for (int r = 0; r < 4; ++r)
                #pragma unroll
                for (int c = 0; c < 4; ++c)
                    acc[r][c] += a[r] * w[c];
        }
    }

    float part[4];
    #pragma unroll
    for (int r = 0; r < 4; ++r) {
        part[r] = 0.f;
        #pragma unroll
        for (int c = 0; c < 4; ++c) {
            int h = h0 + tx * 4 + c;
            float v = tanhf(acc[r][c] + ab1[h]);
            part[r] += v * aw2[h];
        }
    }
    // reduce over the 16 tx lanes (same ty share rows)
    #pragma unroll
    for (int r = 0; r < 4; ++r) {
        #pragma unroll
        for (int o = 1; o < 16; o <<= 1)
            part[r] += __shfl_xor(part[r], o);
    }
    if (tx == 0) {
        #pragma unroll
        for (int r = 0; r < 4; ++r)
            atomicAdd(&scores[r0 + ty * 4 + r], part[r]);
    }
}

// ---------------------------------------------------------------------------
// Per-batch softmax over T and attention pooling -> features[b][512]
// ---------------------------------------------------------------------------
__global__ __launch_bounds__(256) void attn_pool(
    const float* __restrict__ scores, const float* __restrict__ hist,
    float* __restrict__ features)
{
    int b = blockIdx.x;
    int tid = threadIdx.x;
    __shared__ float w[T_SZ];
    __shared__ float smax[4], ssum[4];

    float sc = (tid < T_SZ) ? scores[(size_t)tid * B_SZ + b] : -INFINITY;
    float m = sc;
    for (int o = 32; o; o >>= 1) m = fmaxf(m, __shfl_xor(m, o));
    if ((tid & 63) == 0) smax[tid >> 6] = m;
    __syncthreads();
    float M = fmaxf(fmaxf(smax[0], smax[1]), fmaxf(smax[2], smax[3]));
    float e = (tid < T_SZ) ? expf(sc - M) : 0.f;
    float se = e;
    for (int o = 32; o; o >>= 1) se += __shfl_xor(se, o);
    if ((tid & 63) == 0) ssum[tid >> 6] = se;
    __syncthreads();
    float S = ssum[0] + ssum[1] + ssum[2] + ssum[3];
    if (tid < T_SZ) w[tid] = e / S;
    __syncthreads();

    for (int e0 = tid; e0 < E_SZ; e0 += 256) {
        float acc = 0.f;
        for (int t = 0; t < T_SZ; ++t)
            acc += w[t] * hist[(((size_t)t * B_SZ) + b) * E_SZ + e0];
        features[(size_t)b * E_SZ + e0] = acc;
    }
}

// ---------------------------------------------------------------------------
// FC: logits[b][343] = features[b] . fc_w[o] + fc_b[o]
// ---------------------------------------------------------------------------
__global__ __launch_bounds__(256) void fc_kernel(
    const float* __restrict__ features, const float* __restrict__ fc_w,
    const float* __restrict__ fc_b, float* __restrict__ logits)
{
    int b = blockIdx.x;
    int tid = threadIdx.x;
    __shared__ float f[E_SZ];
    f[tid] = features[(size_t)b * E_SZ + tid];
    f[tid + 256] = features[(size_t)b * E_SZ + tid + 256];
    __syncthreads();
    for (int o = tid; o < K_SZ * L_SZ; o += 256) {
        const float* wr = fc_w + (size_t)o * E_SZ;
        float acc = fc_b[o];
        for (int e = 0; e < E_SZ; ++e) acc += f[e] * wr[e];
        logits[(size_t)b * (K_SZ * L_SZ) + o] = acc;
    }
}

// ---------------------------------------------------------------------------
// CRF loss per batch element: per_loss[b] = logZ - gold_score
// ---------------------------------------------------------------------------
__global__ __launch_bounds__(64) void crf_kernel(
    const float* __restrict__ logits, const int* __restrict__ labels,
    const float* __restrict__ start_t, const float* __restrict__ trans,
    const float* __restrict__ end_t, float* __restrict__ per_loss)
{
    int b = blockIdx.x;
    int tid = threadIdx.x;
    __shared__ float tr[K_SZ * K_SZ];
    __shared__ float em[K_SZ * L_SZ];
    __shared__ float alpha[K_SZ];

    for (int i = tid; i < K_SZ * K_SZ; i += 64) tr[i] = trans[i];
    for (int i = tid; i < K_SZ * L_SZ; i += 64)
        em[i] = logits[(size_t)b * (K_SZ * L_SZ) + i];
    __syncthreads();
    if (tid < K_SZ) alpha[tid] = start_t[tid] + em[tid];
    __syncthreads();

    for (int t = 1; t < L_SZ; ++t) {
        float na = 0.f;
        if (tid < K_SZ) {
            float m = -INFINITY;
            for (int k = 0; k < K_SZ; ++k)
                m = fmaxf(m, alpha[k] + tr[k * K_SZ + tid]);
            float s = 0.f;
            for (int k = 0; k < K_SZ; ++k)
                s += expf(alpha[k] + tr[k * K_SZ + tid] - m);
            na = m + logf(s) + em[t * K_SZ + tid];
        }
        __syncthreads();
        if (tid < K_SZ) alpha[tid] = na;
        __syncthreads();
    }

    float v = (tid < K_SZ) ? alpha[tid] + end_t[tid] : -INFINITY;
    float m = v;
    for (int o = 32; o; o >>= 1) m = fmaxf(m, __shfl_xor(m, o));
    float e = (tid < K_SZ) ? expf(v - m) : 0.f;
    for (int o = 32; o; o >>= 1) e += __shfl_xor(e, o);
    float logZ = m + logf(e);

    if (tid == 0) {
        const int* lab = labels + (size_t)b * L_SZ;
        float score = start_t[lab[0]] + end_t[lab[L_SZ - 1]];
        for (int t = 0; t < L_SZ; ++t) score += em[t * K_SZ + lab[t]];
        for (int t = 0; t < L_SZ - 1; ++t) score += tr[lab[t] * K_SZ + lab[t + 1]];
        per_loss[b] = logZ - score;
    }
}

// ---------------------------------------------------------------------------
// Mean reduce 512 -> scalar
// ---------------------------------------------------------------------------
__global__ __launch_bounds__(256) void reduce_kernel(
    const float* __restrict__ per_loss, float* __restrict__ out)
{
    int tid = threadIdx.x;
    float s = per_loss[tid] + per_loss[tid + 256];
    for (int o = 32; o; o >>= 1) s += __shfl_xor(s, o);
    __shared__ float part[4];
    if ((tid & 63) == 0) part[tid >> 6] = s;
    __syncthreads();
    if (tid == 0) out[0] = (part[0] + part[1] + part[2] + part[3]) / (float)B_SZ;
}

// ---------------------------------------------------------------------------
extern "C" void kernel_launch(void* const* d_in, const int* in_sizes, int n_in,
                              void* d_out, int out_size, void* d_ws, size_t ws_size,
                              hipStream_t stream)
{
    const float* x      = (const float*)d_in[0];
    const int*   labels = (const int*)d_in[1];
    const float* w_ih_f = (const float*)d_in[2];
    const float* w_hh_f = (const float*)d_in[3];
    const float* b_f    = (const float*)d_in[4];
    const float* w_ih_b = (const float*)d_in[5];
    const float* w_hh_b = (const float*)d_in[6];
    const float* b_b    = (const float*)d_in[7];
    const float* aw1    = (const float*)d_in[8];
    const float* ab1    = (const float*)d_in[9];
    const float* aw2    = (const float*)d_in[10];
    // d_in[11] = ab2 : constant added to all scores -> softmax-invariant, unused
    const float* fc_w   = (const float*)d_in[12];
    const float* fc_b   = (const float*)d_in[13];
    const float* start_t = (const float*)d_in[14];
    const float* trans   = (const float*)d_in[15];
    const float* end_t   = (const float*)d_in[16];
    float* out = (float*)d_out;

    char* ws = (char*)d_ws;
    size_t off = 0;
    float* Wp       = (float*)(ws + off); off += (size_t)NP_SZ * KK_SZ * 4;        // 3,145,728
    float* bp       = (float*)(ws + off); off += (size_t)NP_SZ * 4;                // 8,192
    float* cstate   = (float*)(ws + off); off += (size_t)2 * B_SZ * H_SZ * 4;      // 1,048,576
    float* hist     = (float*)(ws + off); off += (size_t)T_SZ * B_SZ * E_SZ * 4;   // 134,217,728
    float* scores   = (float*)(ws + off); off += (size_t)T_SZ * B_SZ * 4;          // 262,144
    float* features = (float*)(ws + off); off += (size_t)B_SZ * E_SZ * 4;          // 1,048,576
    float* logits   = (float*)(ws + off); off += (size_t)B_SZ * K_SZ * L_SZ * 4;   // 702,464
    float* per_loss = (float*)(ws + off); off += (size_t)B_SZ * 4;

    // 1. permute weights
    prep_kernel<<<(NP_SZ * KK_SZ + 255) / 256, 256, 0, stream>>>(
        w_ih_f, w_hh_f, b_f, w_ih_b, w_hh_b, b_b, Wp, bp);

    // 2. zero the score accumulator (ws is poisoned before every launch)
    hipMemsetAsync(scores, 0, (size_t)T_SZ * B_SZ * 4, stream);

    // 3. BiLSTM: 128 sequential fused steps
    for (int s = 0; s < T_SZ; ++s)
        lstm_step<<<256, 256, 0, stream>>>(s, x, Wp, bp, hist, cstate);

    // 4. attention MLP scores
    attn_gemm<<<4096, 256, 0, stream>>>(hist, aw1, ab1, aw2, scores);

    // 5. softmax + pooling
    attn_pool<<<B_SZ, 256, 0, stream>>>(scores, hist, features);

    // 6. FC to emissions
    fc_kernel<<<B_SZ, 256, 0, stream>>>(features, fc_w, fc_b, logits);

    // 7. CRF loss per batch element
    crf_kernel<<<B_SZ, 64, 0, stream>>>(logits, labels, start_t, trans, end_t, per_loss);

    // 8. mean
    reduce_kernel<<<1, 256, 0, stream>>>(per_loss, out);
}

// Round 2
// 3056.643 us; speedup vs baseline: 1.1937x; 1.1937x over previous
//
#include <hip/hip_runtime.h>
#include <math.h>

// Problem constants
#define B_SZ 512
#define T_SZ 128
#define D_SZ 128
#define H_SZ 256
#define K_SZ 49
#define L_SZ 7
#define E_SZ 512   // 2H
#define KK_SZ 384  // H + D fused K dim (h | x)

typedef float f32x4 __attribute__((ext_vector_type(4)));
typedef short bf16x8 __attribute__((ext_vector_type(8)));

__device__ __forceinline__ float sigm(float x) { return 1.0f / (1.0f + expf(-x)); }

__device__ __forceinline__ unsigned short f2bf(float f) {
    union { float f; unsigned u; } v; v.f = f;
    unsigned r = v.u + 0x7FFFu + ((v.u >> 16) & 1u);
    return (unsigned short)(r >> 16);
}
__device__ __forceinline__ float bf2f(unsigned short h) {
    union { unsigned u; float f; } v; v.u = ((unsigned)h) << 16;
    return v.f;
}

// ---------------------------------------------------------------------------
// Weight prep: Wt bf16 in MFMA B-fragment streaming order.
// Wt[dir][w][kk][hi][nl][e]   (2 x 8 x 12 x 4 x 128 x 8)
// nl = p*64 + g*16 + u ; h-cell j = w*32 + p*16 + u ; orig row = g*256 + j
// k = kk*32 + hi*8 + e ; k<256 -> w_hh[row][k], else w_ih[row][k-256]
// bp[dir][w][nl] = combined bias (fp32)
// ---------------------------------------------------------------------------
__global__ __launch_bounds__(256) void prep_w(
    const float* __restrict__ w_ih_f, const float* __restrict__ w_hh_f,
    const float* __restrict__ b_f, const float* __restrict__ w_ih_b,
    const float* __restrict__ w_hh_b, const float* __restrict__ b_b,
    short* __restrict__ Wt, float* __restrict__ bp)
{
    int idx = blockIdx.x * 256 + threadIdx.x;
    if (idx >= 2 * 8 * 12 * 4 * 128 * 8) return;
    int tmp = idx;
    int e  = tmp & 7;   tmp >>= 3;
    int nl = tmp & 127; tmp >>= 7;
    int hi = tmp & 3;   tmp >>= 2;
    int kk = tmp % 12;  tmp /= 12;
    int w  = tmp & 7;   tmp >>= 3;
    int dir = tmp;
    int p = nl >> 6, g = (nl >> 4) & 3, u = nl & 15;
    int j = w * 32 + p * 16 + u;
    int row = g * H_SZ + j;
    int k = kk * 32 + hi * 8 + e;
    const float* w_ih = dir ? w_ih_b : w_ih_f;
    const float* w_hh = dir ? w_hh_b : w_hh_f;
    float v = (k < H_SZ) ? w_hh[row * H_SZ + k] : w_ih[row * D_SZ + (k - H_SZ)];
    Wt[idx] = (short)f2bf(v);
    if (kk == 0 && hi == 0 && e == 0)
        bp[(dir * 8 + w) * 128 + nl] = (dir ? b_b : b_f)[row];
}

__global__ __launch_bounds__(256) void prep_aw(
    const float* __restrict__ aw1, short* __restrict__ aw1b)
{
    int idx = blockIdx.x * 256 + threadIdx.x;
    if (idx < H_SZ * E_SZ) aw1b[idx] = (short)f2bf(aw1[idx]);
}

// ---------------------------------------------------------------------------
// Persistent BiLSTM: 64 blocks = 32 batch-tiles x 2 dirs, 512 thr (8 waves).
// All 128 timesteps in one launch; h in LDS (bf16 dbuf), c in VGPRs,
// weights streamed from L2 each step as ready-made B fragments.
// Wave w owns gates [w*128, w*128+128) == h-cells [w*32, w*32+32).
// ---------------------------------------------------------------------------
__global__ __launch_bounds__(512) void recur_kernel(
    const float* __restrict__ x, const short* __restrict__ Wt,
    const float* __restrict__ bp, unsigned short* __restrict__ hb)
{
    const int dir = blockIdx.x & 1;
    const int b0 = (blockIdx.x >> 1) * 16;
    const int w = threadIdx.x >> 6;
    const int l = threadIdx.x & 63;
    const int u = l & 15, hi = l >> 4;

    __shared__ unsigned short hs[2][16][264];  // row stride 528B: 16B-aligned, 2-way banks
    __shared__ unsigned short xs[16][136];     // row stride 272B

    // zero h(t=-1)
    for (int i = threadIdx.x; i < (16 * 264 * 2) / 8; i += 512)
        reinterpret_cast<unsigned long long*>(&hs[0][0][0])[i] = 0ull;

    float bias[8];
    #pragma unroll
    for (int f = 0; f < 8; ++f)
        bias[f] = bp[(dir * 8 + w) * 128 + f * 16 + u];

    float c[2][4] = {};
    const short* wbase = Wt + (size_t)(dir * 8 + w) * (12 * 4 * 128 * 8);

    int cur = 0;
    for (int s = 0; s < T_SZ; ++s) {
        const int t = dir ? (T_SZ - 1 - s) : s;

        // stage x_t (fp32 -> bf16): 512 threads x 4 elems
        {
            int row = threadIdx.x >> 5;
            int c0 = (threadIdx.x & 31) * 4;
            float4 xv = *reinterpret_cast<const float4*>(
                x + (((size_t)(b0 + row)) * T_SZ + t) * D_SZ + c0);
            unsigned long long pk =
                (unsigned long long)f2bf(xv.x)
              | ((unsigned long long)f2bf(xv.y) << 16)
              | ((unsigned long long)f2bf(xv.z) << 32)
              | ((unsigned long long)f2bf(xv.w) << 48);
            *reinterpret_cast<unsigned long long*>(&xs[row][c0]) = pk;
        }
        __syncthreads();   // x staged + prev-step h visible

        f32x4 acc[8];
        #pragma unroll
        for (int f = 0; f < 8; ++f) {
            acc[f].x = bias[f]; acc[f].y = bias[f];
            acc[f].z = bias[f]; acc[f].w = bias[f];
        }

        #pragma unroll
        for (int kk = 0; kk < 12; ++kk) {
            bf16x8 a;
            if (kk < 8)
                a = *reinterpret_cast<const bf16x8*>(&hs[cur][u][kk * 32 + hi * 8]);
            else
                a = *reinterpret_cast<const bf16x8*>(&xs[u][(kk - 8) * 32 + hi * 8]);
            const short* wk = wbase + (size_t)(kk * 4 + hi) * (128 * 8);
            #pragma unroll
            for (int f = 0; f < 8; ++f) {
                bf16x8 bfrag = *reinterpret_cast<const bf16x8*>(wk + (f * 16 + u) * 8);
                acc[f] = __builtin_amdgcn_mfma_f32_16x16x32_bf16(a, bfrag, acc[f], 0, 0, 0);
            }
        }

        // epilogue: lane owns rows hi*4+r (batch), cells j = w*32 + p*16 + u
        #pragma unroll
        for (int p = 0; p < 2; ++p) {
            int j = w * 32 + p * 16 + u;
            #pragma unroll
            for (int r = 0; r < 4; ++r) {
                float iv = sigm(acc[p * 4 + 0][r]);
                float fv = sigm(acc[p * 4 + 1][r]);
                float gv = tanhf(acc[p * 4 + 2][r]);
                float ov = sigm(acc[p * 4 + 3][r]);
                float cn = fv * c[p][r] + iv * gv;
                c[p][r] = cn;
                unsigned short hbf = f2bf(ov * tanhf(cn));
                int row = hi * 4 + r;
                hs[cur ^ 1][row][j] = hbf;
                hb[((size_t)t * B_SZ + (b0 + row)) * E_SZ + dir * H_SZ + j] = hbf;
            }
        }
        __syncthreads();   // MFMA x-reads done before next stage; h(next) published
        cur ^= 1;
    }
}

// ---------------------------------------------------------------------------
// Attention MLP scores, bf16 MFMA:
// scores[r] += sum_h aw2[h] * tanh(ab1[h] + sum_e hb[r][e]*aw1[h][e])
// Grid: 1024 = 512 M-tiles(128 rows) x 2 N-tiles(128 cols); 4 waves of 64x64.
// ---------------------------------------------------------------------------
__global__ __launch_bounds__(256) void attn_mfma(
    const unsigned short* __restrict__ hb, const short* __restrict__ aw1b,
    const float* __restrict__ ab1, const float* __restrict__ aw2,
    float* __restrict__ scores)
{
    const int mt = blockIdx.x >> 1, nt = blockIdx.x & 1;
    const int r0 = mt * 128, n0 = nt * 128;
    const int tid = threadIdx.x;
    const int wv = tid >> 6, l = tid & 63, u = l & 15, hi = l >> 4;
    const int mw = wv >> 1, nw = wv & 1;

    __shared__ unsigned short As[128][40];
    __shared__ unsigned short Bs[128][40];

    f32x4 acc[4][4];
    #pragma unroll
    for (int m = 0; m < 4; ++m)
        #pragma unroll
        for (int n = 0; n < 4; ++n)
            acc[m][n] = (f32x4){0.f, 0.f, 0.f, 0.f};

    const int srow = tid >> 1;
    const int sc0 = (tid & 1) * 16;

    for (int k0 = 0; k0 < E_SZ; k0 += 32) {
        bf16x8 va0 = *reinterpret_cast<const bf16x8*>(hb + (size_t)(r0 + srow) * E_SZ + k0 + sc0);
        bf16x8 va1 = *reinterpret_cast<const bf16x8*>(hb + (size_t)(r0 + srow) * E_SZ + k0 + sc0 + 8);
        bf16x8 vb0 = *reinterpret_cast<const bf16x8*>(aw1b + (size_t)(n0 + srow) * E_SZ + k0 + sc0);
        bf16x8 vb1 = *reinterpret_cast<const bf16x8*>(aw1b + (size_t)(n0 + srow) * E_SZ + k0 + sc0 + 8);
        __syncthreads();   // prev-iter frag reads done
        *reinterpret_cast<bf16x8*>(&As[srow][sc0])     = va0;
        *reinterpret_cast<bf16x8*>(&As[srow][sc0 + 8]) = va1;
        *reinterpret_cast<bf16x8*>(&Bs[srow][sc0])     = vb0;
        *reinterpret_cast<bf16x8*>(&Bs[srow][sc0 + 8]) = vb1;
        __syncthreads();

        bf16x8 af[4], bf[4];
        #pragma unroll
        for (int m = 0; m < 4; ++m)
            af[m] = *reinterpret_cast<const bf16x8*>(&As[mw * 64 + m * 16 + u][hi * 8]);
        #pragma unroll
        for (int n = 0; n < 4; ++n)
            bf[n] = *reinterpret_cast<const bf16x8*>(&Bs[nw * 64 + n * 16 + u][hi * 8]);
        #pragma unroll
        for (int m = 0; m < 4; ++m)
            #pragma unroll
            for (int n = 0; n < 4; ++n)
                acc[m][n] = __builtin_amdgcn_mfma_f32_16x16x32_bf16(af[m], bf[n], acc[m][n], 0, 0, 0);
    }

    float t1[4], t2[4];
    #pragma unroll
    for (int n = 0; n < 4; ++n) {
        int h = n0 + nw * 64 + n * 16 + u;
        t1[n] = ab1[h]; t2[n] = aw2[h];
    }
    #pragma unroll
    for (int m = 0; m < 4; ++m) {
        #pragma unroll
        for (int r = 0; r < 4; ++r) {
            float s = 0.f;
            #pragma unroll
            for (int n = 0; n < 4; ++n)
                s += tanhf(acc[m][n][r] + t1[n]) * t2[n];
            #pragma unroll
            for (int o = 1; o < 16; o <<= 1) s += __shfl_xor(s, o);
            if (u == 0)
                atomicAdd(&scores[r0 + mw * 64 + m * 16 + hi * 4 + r], s);
        }
    }
}

// ---------------------------------------------------------------------------
// Per-batch softmax over T + pooling -> features[b][512] (fp32)
// ---------------------------------------------------------------------------
__global__ __launch_bounds__(256) void attn_pool(
    const float* __restrict__ scores, const unsigned short* __restrict__ hb,
    float* __restrict__ features)
{
    int b = blockIdx.x;
    int tid = threadIdx.x;
    __shared__ float w[T_SZ];
    __shared__ float smax[4], ssum[4];

    float sc = (tid < T_SZ) ? scores[(size_t)tid * B_SZ + b] : -INFINITY;
    float m = sc;
    for (int o = 32; o; o >>= 1) m = fmaxf(m, __shfl_xor(m, o));
    if ((tid & 63) == 0) smax[tid >> 6] = m;
    __syncthreads();
    float M = fmaxf(fmaxf(smax[0], smax[1]), fmaxf(smax[2], smax[3]));
    float e = (tid < T_SZ) ? expf(sc - M) : 0.f;
    float se = e;
    for (int o = 32; o; o >>= 1) se += __shfl_xor(se, o);
    if ((tid & 63) == 0) ssum[tid >> 6] = se;
    __syncthreads();
    float S = ssum[0] + ssum[1] + ssum[2] + ssum[3];
    if (tid < T_SZ) w[tid] = e / S;
    __syncthreads();

    for (int e0 = tid; e0 < E_SZ; e0 += 256) {
        float acc = 0.f;
        for (int t = 0; t < T_SZ; ++t)
            acc += w[t] * bf2f(hb[((size_t)t * B_SZ + b) * E_SZ + e0]);
        features[(size_t)b * E_SZ + e0] = acc;
    }
}

// ---------------------------------------------------------------------------
// FC: 64 blocks x 8 batch rows; fc_w re-read 8x less than 1-block-per-b
// ---------------------------------------------------------------------------
__global__ __launch_bounds__(256) void fc_kernel(
    const float* __restrict__ features, const float* __restrict__ fc_w,
    const float* __restrict__ fc_b, float* __restrict__ logits)
{
    int bb = blockIdx.x * 8;
    int tid = threadIdx.x;
    __shared__ float f[8][E_SZ];
    for (int i = tid; i < 8 * E_SZ; i += 256)
        f[i >> 9][i & 511] = features[(size_t)(bb + (i >> 9)) * E_SZ + (i & 511)];
    __syncthreads();
    for (int o = tid; o < K_SZ * L_SZ; o += 256) {
        const float* wr = fc_w + (size_t)o * E_SZ;
        float acc[8];
        float bv = fc_b[o];
        #pragma unroll
        for (int b = 0; b < 8; ++b) acc[b] = bv;
        for (int e0 = 0; e0 < E_SZ; ++e0) {
            float wv = wr[e0];
            #pragma unroll
            for (int b = 0; b < 8; ++b) acc[b] += f[b][e0] * wv;
        }
        #pragma unroll
        for (int b = 0; b < 8; ++b)
            logits[(size_t)(bb + b) * (K_SZ * L_SZ) + o] = acc[b];
    }
}

// ---------------------------------------------------------------------------
// CRF loss per batch element
// ---------------------------------------------------------------------------
__global__ __launch_bounds__(64) void crf_kernel(
    const float* __restrict__ logits, const int* __restrict__ labels,
    const float* __restrict__ start_t, const float* __restrict__ trans,
    const float* __restrict__ end_t, float* __restrict__ per_loss)
{
    int b = blockIdx.x;
    int tid = threadIdx.x;
    __shared__ float tr[K_SZ * K_SZ];
    __shared__ float em[K_SZ * L_SZ];
    __shared__ float alpha[K_SZ];

    for (int i = tid; i < K_SZ * K_SZ; i += 64) tr[i] = trans[i];
    for (int i = tid; i < K_SZ * L_SZ; i += 64)
        em[i] = logits[(size_t)b * (K_SZ * L_SZ) + i];
    __syncthreads();
    if (tid < K_SZ) alpha[tid] = start_t[tid] + em[tid];
    __syncthreads();

    for (int t = 1; t < L_SZ; ++t) {
        float na = 0.f;
        if (tid < K_SZ) {
            float m = -INFINITY;
            for (int k = 0; k < K_SZ; ++k)
                m = fmaxf(m, alpha[k] + tr[k * K_SZ + tid]);
            float s = 0.f;
            for (int k = 0; k < K_SZ; ++k)
                s += expf(alpha[k] + tr[k * K_SZ + tid] - m);
            na = m + logf(s) + em[t * K_SZ + tid];
        }
        __syncthreads();
        if (tid < K_SZ) alpha[tid] = na;
        __syncthreads();
    }

    float v = (tid < K_SZ) ? alpha[tid] + end_t[tid] : -INFINITY;
    float m = v;
    for (int o = 32; o; o >>= 1) m = fmaxf(m, __shfl_xor(m, o));
    float e = (tid < K_SZ) ? expf(v - m) : 0.f;
    for (int o = 32; o; o >>= 1) e += __shfl_xor(e, o);
    float logZ = m + logf(e);

    if (tid == 0) {
        const int* lab = labels + (size_t)b * L_SZ;
        float score = start_t[lab[0]] + end_t[lab[L_SZ - 1]];
        for (int t = 0; t < L_SZ; ++t) score += em[t * K_SZ + lab[t]];
        for (int t = 0; t < L_SZ - 1; ++t) score += tr[lab[t] * K_SZ + lab[t + 1]];
        per_loss[b] = logZ - score;
    }
}

__global__ __launch_bounds__(256) void reduce_kernel(
    const float* __restrict__ per_loss, float* __restrict__ out)
{
    int tid = threadIdx.x;
    float s = per_loss[tid] + per_loss[tid + 256];
    for (int o = 32; o; o >>= 1) s += __shfl_xor(s, o);
    __shared__ float part[4];
    if ((tid & 63) == 0) part[tid >> 6] = s;
    __syncthreads();
    if (tid == 0) out[0] = (part[0] + part[1] + part[2] + part[3]) / (float)B_SZ;
}

// ---------------------------------------------------------------------------
extern "C" void kernel_launch(void* const* d_in, const int* in_sizes, int n_in,
                              void* d_out, int out_size, void* d_ws, size_t ws_size,
                              hipStream_t stream)
{
    const float* x      = (const float*)d_in[0];
    const int*   labels = (const int*)d_in[1];
    const float* w_ih_f = (const float*)d_in[2];
    const float* w_hh_f = (const float*)d_in[3];
    const float* b_f    = (const float*)d_in[4];
    const float* w_ih_b = (const float*)d_in[5];
    const float* w_hh_b = (const float*)d_in[6];
    const float* b_b    = (const float*)d_in[7];
    const float* aw1    = (const float*)d_in[8];
    const float* ab1    = (const float*)d_in[9];
    const float* aw2    = (const float*)d_in[10];
    // d_in[11] = ab2 : softmax-invariant, unused
    const float* fc_w   = (const float*)d_in[12];
    const float* fc_b   = (const float*)d_in[13];
    const float* start_t = (const float*)d_in[14];
    const float* trans   = (const float*)d_in[15];
    const float* end_t   = (const float*)d_in[16];
    float* out = (float*)d_out;

    char* ws = (char*)d_ws;
    size_t off = 0;
    short* Wt        = (short*)(ws + off); off += (size_t)2 * 8 * 12 * 4 * 128 * 8 * 2; // 1.5MB
    float* bp        = (float*)(ws + off); off += (size_t)2048 * 4;
    short* aw1b      = (short*)(ws + off); off += (size_t)H_SZ * E_SZ * 2;              // 256KB
    unsigned short* hb = (unsigned short*)(ws + off); off += (size_t)T_SZ * B_SZ * E_SZ * 2; // 33.5MB
    float* scores    = (float*)(ws + off); off += (size_t)T_SZ * B_SZ * 4;
    float* features  = (float*)(ws + off); off += (size_t)B_SZ * E_SZ * 4;
    float* logits    = (float*)(ws + off); off += (size_t)B_SZ * K_SZ * L_SZ * 4;
    float* per_loss  = (float*)(ws + off); off += (size_t)B_SZ * 4;

    // 1. weight/bias prep into MFMA fragment order
    prep_w<<<(2 * 8 * 12 * 4 * 128 * 8 + 255) / 256, 256, 0, stream>>>(
        w_ih_f, w_hh_f, b_f, w_ih_b, w_hh_b, b_b, Wt, bp);
    prep_aw<<<(H_SZ * E_SZ + 255) / 256, 256, 0, stream>>>(aw1, aw1b);

    // 2. zero score accumulator
    hipMemsetAsync(scores, 0, (size_t)T_SZ * B_SZ * 4, stream);

    // 3. BiLSTM — one persistent launch, all 128 steps
    recur_kernel<<<64, 512, 0, stream>>>(x, Wt, bp, hb);

    // 4. attention MLP scores (bf16 MFMA)
    attn_mfma<<<1024, 256, 0, stream>>>(hb, aw1b, ab1, aw2, scores);

    // 5. softmax + pooling
    attn_pool<<<B_SZ, 256, 0, stream>>>(scores, hb, features);

    // 6. FC to emissions
    fc_kernel<<<64, 256, 0, stream>>>(features, fc_w, fc_b, logits);

    // 7. CRF loss
    crf_kernel<<<B_SZ, 64, 0, stream>>>(logits, labels, start_t, trans, end_t, per_loss);

    // 8. mean
    reduce_kernel<<<1, 256, 0, stream>>>(per_loss, out);
}

// Round 3
// 2442.099 us; speedup vs baseline: 1.4941x; 1.2516x over previous
//
#include <hip/hip_runtime.h>
#include <math.h>

// Problem constants
#define B_SZ 512
#define T_SZ 128
#define D_SZ 128
#define H_SZ 256
#define K_SZ 49
#define L_SZ 7
#define E_SZ 512   // 2H

typedef float f32x4 __attribute__((ext_vector_type(4)));
typedef short bf16x8 __attribute__((ext_vector_type(8)));

__device__ __forceinline__ unsigned short f2bf(float f) {
    union { float f; unsigned u; } v; v.f = f;
    unsigned r = v.u + 0x7FFFu + ((v.u >> 16) & 1u);
    return (unsigned short)(r >> 16);
}
__device__ __forceinline__ float bf2f(unsigned short h) {
    union { unsigned u; float f; } v; v.u = ((unsigned)h) << 16;
    return v.f;
}
__device__ __forceinline__ float fsigm(float x) {
    // 1/(1+e^-x); e^-x may be inf for very negative x -> 1/inf = 0, safe
    return __fdividef(1.0f, 1.0f + __expf(-x));
}
__device__ __forceinline__ float ftanh(float x) {
    x = fminf(fmaxf(x, -20.0f), 20.0f);    // avoid inf/inf
    float e = __expf(2.0f * x);
    return __fdividef(e - 1.0f, e + 1.0f);
}

// ---------------------------------------------------------------------------
// Weight prep into per-wave VGPR-fragment order:
// idx = (((((dir*16 + wv)*12 + kk)*4 + hi)*4 + g)*16 + u)*8 + e
// gate column n' within dir: cell j = wv*16+u, gate g; original row = g*256 + j
// k = kk*32 + hi*8 + e ; k<256 -> w_hh[row][k] else w_ih[row][k-256]
// bp[(dir*4+g)*256 + j] = combined bias
// ---------------------------------------------------------------------------
__global__ __launch_bounds__(256) void prep_w(
    const float* __restrict__ w_ih_f, const float* __restrict__ w_hh_f,
    const float* __restrict__ b_f, const float* __restrict__ w_ih_b,
    const float* __restrict__ w_hh_b, const float* __restrict__ b_b,
    short* __restrict__ Wt, float* __restrict__ bp)
{
    int idx = blockIdx.x * 256 + threadIdx.x;
    if (idx >= 2 * 16 * 12 * 4 * 4 * 128) return;
    int e  = idx & 7;
    int u  = (idx >> 3) & 15;
    int g  = (idx >> 7) & 3;
    int hi = (idx >> 9) & 3;
    int t  = idx >> 11;          // 0..383
    int kk = t % 12;
    int wv = (t / 12) & 15;
    int dir = t / 192;
    int j = wv * 16 + u;
    int row = g * H_SZ + j;
    int k = kk * 32 + hi * 8 + e;
    const float* w_ih = dir ? w_ih_b : w_ih_f;
    const float* w_hh = dir ? w_hh_b : w_hh_f;
    float v = (k < H_SZ) ? w_hh[row * H_SZ + k] : w_ih[row * D_SZ + (k - H_SZ)];
    Wt[idx] = (short)f2bf(v);
    if (kk == 0 && hi == 0 && e == 0)
        bp[(dir * 4 + g) * 256 + j] = (dir ? b_b : b_f)[row];
}

__global__ __launch_bounds__(256) void prep_aw(
    const float* __restrict__ aw1, short* __restrict__ aw1b)
{
    int idx = blockIdx.x * 256 + threadIdx.x;
    if (idx < H_SZ * E_SZ) aw1b[idx] = (short)f2bf(aw1[idx]);
}

// x fp32 -> bf16, same [B][T][D] layout
__global__ __launch_bounds__(256) void xprep(
    const float* __restrict__ x, unsigned short* __restrict__ xb)
{
    size_t i = ((size_t)blockIdx.x * 256 + threadIdx.x) * 4;
    float4 v = *reinterpret_cast<const float4*>(x + i);
    unsigned long long pk =
        (unsigned long long)f2bf(v.x)
      | ((unsigned long long)f2bf(v.y) << 16)
      | ((unsigned long long)f2bf(v.z) << 32)
      | ((unsigned long long)f2bf(v.w) << 48);
    *reinterpret_cast<unsigned long long*>(xb + i) = pk;
}

// ---------------------------------------------------------------------------
// Persistent BiLSTM, weights VGPR-resident.
// 64 blocks = 32 batch-tiles(16 rows) x 2 dirs, 1024 threads (16 waves).
// Wave wv owns 64 gate-cols = cells [wv*16, wv*16+16) x 4 gates.
// Per lane: 48 bf16x8 weight frags (192 VGPR), c[4], h via LDS dbuf.
// ---------------------------------------------------------------------------
__global__ __launch_bounds__(1024) void recur_kernel(
    const unsigned short* __restrict__ xb, const short* __restrict__ Wt,
    const float* __restrict__ bp, unsigned short* __restrict__ hb)
{
    const int dir = blockIdx.x & 1;
    const int b0 = (blockIdx.x >> 1) * 16;
    const int wv = threadIdx.x >> 6;
    const int l  = threadIdx.x & 63;
    const int u = l & 15, hi = l >> 4;

    __shared__ unsigned short hs[2][16][264];  // row stride 528B -> 2-way banks (free)
    __shared__ unsigned short xs[16][136];

    // zero hs[0] (A-operand for step 0)
    for (int i = threadIdx.x; i < 16 * 264 / 2; i += 1024)
        reinterpret_cast<unsigned*>(&hs[0][0][0])[i] = 0u;

    // resident weights: 48 fragments/lane
    const short* wbase = Wt + ((size_t)(dir * 16 + wv) * 12) * 2048 + u * 8;
    bf16x8 wreg[12][4];
    #pragma unroll
    for (int kk = 0; kk < 12; ++kk)
        #pragma unroll
        for (int g = 0; g < 4; ++g)
            wreg[kk][g] = *reinterpret_cast<const bf16x8*>(
                wbase + kk * 2048 + hi * 512 + g * 128);

    const int j = wv * 16 + u;   // owned h-cell
    float bias[4];
    #pragma unroll
    for (int g = 0; g < 4; ++g)
        bias[g] = bp[(dir * 4 + g) * 256 + j];

    // x staging: thread covers (xrow, dword xcol/2)
    const int xrow = threadIdx.x >> 6;
    const int xcol = (threadIdx.x & 63) * 2;
    int t0 = dir ? (T_SZ - 1) : 0;
    unsigned xreg = *reinterpret_cast<const unsigned*>(
        xb + ((size_t)(b0 + xrow) * T_SZ + t0) * D_SZ + xcol);

    float c[4] = {0.f, 0.f, 0.f, 0.f};
    int cur = 0;

    for (int s = 0; s < T_SZ; ++s) {
        const int t = dir ? (T_SZ - 1 - s) : s;

        __syncthreads();   // prev MFMA xs reads done; prev hs writes visible; hs[0] zero visible
        *reinterpret_cast<unsigned*>(&xs[xrow][xcol]) = xreg;
        if (s + 1 < T_SZ) {
            int tn = dir ? (T_SZ - 2 - s) : (s + 1);
            xreg = *reinterpret_cast<const unsigned*>(
                xb + ((size_t)(b0 + xrow) * T_SZ + tn) * D_SZ + xcol);
        }
        __syncthreads();   // xs visible

        f32x4 acc[4];
        #pragma unroll
        for (int g = 0; g < 4; ++g) {
            acc[g].x = bias[g]; acc[g].y = bias[g];
            acc[g].z = bias[g]; acc[g].w = bias[g];
        }

        #pragma unroll
        for (int kk = 0; kk < 12; ++kk) {
            bf16x8 a;
            if (kk < 8)
                a = *reinterpret_cast<const bf16x8*>(&hs[cur][u][kk * 32 + hi * 8]);
            else
                a = *reinterpret_cast<const bf16x8*>(&xs[u][(kk - 8) * 32 + hi * 8]);
            #pragma unroll
            for (int g = 0; g < 4; ++g)
                acc[g] = __builtin_amdgcn_mfma_f32_16x16x32_bf16(a, wreg[kk][g], acc[g], 0, 0, 0);
        }

        // epilogue: lane -> rows hi*4+r, cell j, gates in acc[0..3][r]
        #pragma unroll
        for (int r = 0; r < 4; ++r) {
            float iv = fsigm(acc[0][r]);
            float fv = fsigm(acc[1][r]);
            float gv = ftanh(acc[2][r]);
            float ov = fsigm(acc[3][r]);
            float cn = fv * c[r] + iv * gv;
            c[r] = cn;
            unsigned short hv = f2bf(ov * ftanh(cn));
            int row = hi * 4 + r;
            hs[cur ^ 1][row][j] = hv;
            hb[((size_t)t * B_SZ + b0 + row) * E_SZ + dir * H_SZ + j] = hv;
        }
        cur ^= 1;
    }
}

// ---------------------------------------------------------------------------
// Attention MLP scores, bf16 MFMA (unchanged from round 2)
// ---------------------------------------------------------------------------
__global__ __launch_bounds__(256) void attn_mfma(
    const unsigned short* __restrict__ hb, const short* __restrict__ aw1b,
    const float* __restrict__ ab1, const float* __restrict__ aw2,
    float* __restrict__ scores)
{
    const int mt = blockIdx.x >> 1, nt = blockIdx.x & 1;
    const int r0 = mt * 128, n0 = nt * 128;
    const int tid = threadIdx.x;
    const int wv = tid >> 6, l = tid & 63, u = l & 15, hi = l >> 4;
    const int mw = wv >> 1, nw = wv & 1;

    __shared__ unsigned short As[128][40];
    __shared__ unsigned short Bs[128][40];

    f32x4 acc[4][4];
    #pragma unroll
    for (int m = 0; m < 4; ++m)
        #pragma unroll
        for (int n = 0; n < 4; ++n)
            acc[m][n] = (f32x4){0.f, 0.f, 0.f, 0.f};

    const int srow = tid >> 1;
    const int sc0 = (tid & 1) * 16;

    for (int k0 = 0; k0 < E_SZ; k0 += 32) {
        bf16x8 va0 = *reinterpret_cast<const bf16x8*>(hb + (size_t)(r0 + srow) * E_SZ + k0 + sc0);
        bf16x8 va1 = *reinterpret_cast<const bf16x8*>(hb + (size_t)(r0 + srow) * E_SZ + k0 + sc0 + 8);
        bf16x8 vb0 = *reinterpret_cast<const bf16x8*>(aw1b + (size_t)(n0 + srow) * E_SZ + k0 + sc0);
        bf16x8 vb1 = *reinterpret_cast<const bf16x8*>(aw1b + (size_t)(n0 + srow) * E_SZ + k0 + sc0 + 8);
        __syncthreads();
        *reinterpret_cast<bf16x8*>(&As[srow][sc0])     = va0;
        *reinterpret_cast<bf16x8*>(&As[srow][sc0 + 8]) = va1;
        *reinterpret_cast<bf16x8*>(&Bs[srow][sc0])     = vb0;
        *reinterpret_cast<bf16x8*>(&Bs[srow][sc0 + 8]) = vb1;
        __syncthreads();

        bf16x8 af[4], bf[4];
        #pragma unroll
        for (int m = 0; m < 4; ++m)
            af[m] = *reinterpret_cast<const bf16x8*>(&As[mw * 64 + m * 16 + u][hi * 8]);
        #pragma unroll
        for (int n = 0; n < 4; ++n)
            bf[n] = *reinterpret_cast<const bf16x8*>(&Bs[nw * 64 + n * 16 + u][hi * 8]);
        #pragma unroll
        for (int m = 0; m < 4; ++m)
            #pragma unroll
            for (int n = 0; n < 4; ++n)
                acc[m][n] = __builtin_amdgcn_mfma_f32_16x16x32_bf16(af[m], bf[n], acc[m][n], 0, 0, 0);
    }

    float t1[4], t2[4];
    #pragma unroll
    for (int n = 0; n < 4; ++n) {
        int h = n0 + nw * 64 + n * 16 + u;
        t1[n] = ab1[h]; t2[n] = aw2[h];
    }
    #pragma unroll
    for (int m = 0; m < 4; ++m) {
        #pragma unroll
        for (int r = 0; r < 4; ++r) {
            float s = 0.f;
            #pragma unroll
            for (int n = 0; n < 4; ++n)
                s += tanhf(acc[m][n][r] + t1[n]) * t2[n];
            #pragma unroll
            for (int o = 1; o < 16; o <<= 1) s += __shfl_xor(s, o);
            if (u == 0)
                atomicAdd(&scores[r0 + mw * 64 + m * 16 + hi * 4 + r], s);
        }
    }
}

// ---------------------------------------------------------------------------
// Per-batch softmax over T + pooling -> features[b][512]
// ---------------------------------------------------------------------------
__global__ __launch_bounds__(256) void attn_pool(
    const float* __restrict__ scores, const unsigned short* __restrict__ hb,
    float* __restrict__ features)
{
    int b = blockIdx.x;
    int tid = threadIdx.x;
    __shared__ float w[T_SZ];
    __shared__ float smax[4], ssum[4];

    float sc = (tid < T_SZ) ? scores[(size_t)tid * B_SZ + b] : -INFINITY;
    float m = sc;
    for (int o = 32; o; o >>= 1) m = fmaxf(m, __shfl_xor(m, o));
    if ((tid & 63) == 0) smax[tid >> 6] = m;
    __syncthreads();
    float M = fmaxf(fmaxf(smax[0], smax[1]), fmaxf(smax[2], smax[3]));
    float e = (tid < T_SZ) ? expf(sc - M) : 0.f;
    float se = e;
    for (int o = 32; o; o >>= 1) se += __shfl_xor(se, o);
    if ((tid & 63) == 0) ssum[tid >> 6] = se;
    __syncthreads();
    float S = ssum[0] + ssum[1] + ssum[2] + ssum[3];
    if (tid < T_SZ) w[tid] = e / S;
    __syncthreads();

    for (int e0 = tid; e0 < E_SZ; e0 += 256) {
        float acc = 0.f;
        for (int t = 0; t < T_SZ; ++t)
            acc += w[t] * bf2f(hb[((size_t)t * B_SZ + b) * E_SZ + e0]);
        features[(size_t)b * E_SZ + e0] = acc;
    }
}

// ---------------------------------------------------------------------------
// FC: 64 blocks x 8 batch rows
// ---------------------------------------------------------------------------
__global__ __launch_bounds__(256) void fc_kernel(
    const float* __restrict__ features, const float* __restrict__ fc_w,
    const float* __restrict__ fc_b, float* __restrict__ logits)
{
    int bb = blockIdx.x * 8;
    int tid = threadIdx.x;
    __shared__ float f[8][E_SZ];
    for (int i = tid; i < 8 * E_SZ; i += 256)
        f[i >> 9][i & 511] = features[(size_t)(bb + (i >> 9)) * E_SZ + (i & 511)];
    __syncthreads();
    for (int o = tid; o < K_SZ * L_SZ; o += 256) {
        const float* wr = fc_w + (size_t)o * E_SZ;
        float acc[8];
        float bv = fc_b[o];
        #pragma unroll
        for (int b = 0; b < 8; ++b) acc[b] = bv;
        for (int e0 = 0; e0 < E_SZ; ++e0) {
            float wv = wr[e0];
            #pragma unroll
            for (int b = 0; b < 8; ++b) acc[b] += f[b][e0] * wv;
        }
        #pragma unroll
        for (int b = 0; b < 8; ++b)
            logits[(size_t)(bb + b) * (K_SZ * L_SZ) + o] = acc[b];
    }
}

// ---------------------------------------------------------------------------
// CRF loss per batch element
// ---------------------------------------------------------------------------
__global__ __launch_bounds__(64) void crf_kernel(
    const float* __restrict__ logits, const int* __restrict__ labels,
    const float* __restrict__ start_t, const float* __restrict__ trans,
    const float* __restrict__ end_t, float* __restrict__ per_loss)
{
    int b = blockIdx.x;
    int tid = threadIdx.x;
    __shared__ float tr[K_SZ * K_SZ];
    __shared__ float em[K_SZ * L_SZ];
    __shared__ float alpha[K_SZ];

    for (int i = tid; i < K_SZ * K_SZ; i += 64) tr[i] = trans[i];
    for (int i = tid; i < K_SZ * L_SZ; i += 64)
        em[i] = logits[(size_t)b * (K_SZ * L_SZ) + i];
    __syncthreads();
    if (tid < K_SZ) alpha[tid] = start_t[tid] + em[tid];
    __syncthreads();

    for (int t = 1; t < L_SZ; ++t) {
        float na = 0.f;
        if (tid < K_SZ) {
            float m = -INFINITY;
            for (int k = 0; k < K_SZ; ++k)
                m = fmaxf(m, alpha[k] + tr[k * K_SZ + tid]);
            float s = 0.f;
            for (int k = 0; k < K_SZ; ++k)
                s += expf(alpha[k] + tr[k * K_SZ + tid] - m);
            na = m + logf(s) + em[t * K_SZ + tid];
        }
        __syncthreads();
        if (tid < K_SZ) alpha[tid] = na;
        __syncthreads();
    }

    float v = (tid < K_SZ) ? alpha[tid] + end_t[tid] : -INFINITY;
    float m = v;
    for (int o = 32; o; o >>= 1) m = fmaxf(m, __shfl_xor(m, o));
    float e = (tid < K_SZ) ? expf(v - m) : 0.f;
    for (int o = 32; o; o >>= 1) e += __shfl_xor(e, o);
    float logZ = m + logf(e);

    if (tid == 0) {
        const int* lab = labels + (size_t)b * L_SZ;
        float score = start_t[lab[0]] + end_t[lab[L_SZ - 1]];
        for (int t = 0; t < L_SZ; ++t) score += em[t * K_SZ + lab[t]];
        for (int t = 0; t < L_SZ - 1; ++t) score += tr[lab[t] * K_SZ + lab[t + 1]];
        per_loss[b] = logZ - score;
    }
}

__global__ __launch_bounds__(256) void reduce_kernel(
    const float* __restrict__ per_loss, float* __restrict__ out)
{
    int tid = threadIdx.x;
    float s = per_loss[tid] + per_loss[tid + 256];
    for (int o = 32; o; o >>= 1) s += __shfl_xor(s, o);
    __shared__ float part[4];
    if ((tid & 63) == 0) part[tid >> 6] = s;
    __syncthreads();
    if (tid == 0) out[0] = (part[0] + part[1] + part[2] + part[3]) / (float)B_SZ;
}

// ---------------------------------------------------------------------------
extern "C" void kernel_launch(void* const* d_in, const int* in_sizes, int n_in,
                              void* d_out, int out_size, void* d_ws, size_t ws_size,
                              hipStream_t stream)
{
    const float* x      = (const float*)d_in[0];
    const int*   labels = (const int*)d_in[1];
    const float* w_ih_f = (const float*)d_in[2];
    const float* w_hh_f = (const float*)d_in[3];
    const float* b_f    = (const float*)d_in[4];
    const float* w_ih_b = (const float*)d_in[5];
    const float* w_hh_b = (const float*)d_in[6];
    const float* b_b    = (const float*)d_in[7];
    const float* aw1    = (const float*)d_in[8];
    const float* ab1    = (const float*)d_in[9];
    const float* aw2    = (const float*)d_in[10];
    // d_in[11] = ab2 : softmax-invariant, unused
    const float* fc_w   = (const float*)d_in[12];
    const float* fc_b   = (const float*)d_in[13];
    const float* start_t = (const float*)d_in[14];
    const float* trans   = (const float*)d_in[15];
    const float* end_t   = (const float*)d_in[16];
    float* out = (float*)d_out;

    char* ws = (char*)d_ws;
    size_t off = 0;
    short* Wt        = (short*)(ws + off); off += (size_t)2 * 16 * 12 * 4 * 4 * 128 * 2; // 1.5MB
    float* bp        = (float*)(ws + off); off += (size_t)2048 * 4;
    short* aw1b      = (short*)(ws + off); off += (size_t)H_SZ * E_SZ * 2;
    unsigned short* xb = (unsigned short*)(ws + off); off += (size_t)B_SZ * T_SZ * D_SZ * 2; // 16.8MB
    unsigned short* hb = (unsigned short*)(ws + off); off += (size_t)T_SZ * B_SZ * E_SZ * 2; // 33.5MB
    float* scores    = (float*)(ws + off); off += (size_t)T_SZ * B_SZ * 4;
    float* features  = (float*)(ws + off); off += (size_t)B_SZ * E_SZ * 4;
    float* logits    = (float*)(ws + off); off += (size_t)B_SZ * K_SZ * L_SZ * 4;
    float* per_loss  = (float*)(ws + off); off += (size_t)B_SZ * 4;

    // 1. weight/bias/x prep
    prep_w<<<(2 * 16 * 12 * 4 * 4 * 128 + 255) / 256, 256, 0, stream>>>(
        w_ih_f, w_hh_f, b_f, w_ih_b, w_hh_b, b_b, Wt, bp);
    prep_aw<<<(H_SZ * E_SZ + 255) / 256, 256, 0, stream>>>(aw1, aw1b);
    xprep<<<(B_SZ * T_SZ * D_SZ / 4 + 255) / 256, 256, 0, stream>>>(x, xb);

    // 2. zero score accumulator
    hipMemsetAsync(scores, 0, (size_t)T_SZ * B_SZ * 4, stream);

    // 3. BiLSTM — one persistent launch, weights VGPR-resident
    recur_kernel<<<64, 1024, 0, stream>>>(xb, Wt, bp, hb);

    // 4. attention MLP scores (bf16 MFMA)
    attn_mfma<<<1024, 256, 0, stream>>>(hb, aw1b, ab1, aw2, scores);

    // 5. softmax + pooling
    attn_pool<<<B_SZ, 256, 0, stream>>>(scores, hb, features);

    // 6. FC to emissions
    fc_kernel<<<64, 256, 0, stream>>>(features, fc_w, fc_b, logits);

    // 7. CRF loss
    crf_kernel<<<B_SZ, 64, 0, stream>>>(logits, labels, start_t, trans, end_t, per_loss);

    // 8. mean
    reduce_kernel<<<1, 256, 0, stream>>>(per_loss, out);
}

// Round 4
// 969.949 us; speedup vs baseline: 3.7617x; 2.5178x over previous
//
#include <hip/hip_runtime.h>
#include <math.h>

// Problem constants
#define B_SZ 512
#define T_SZ 128
#define D_SZ 128
#define H_SZ 256
#define K_SZ 49
#define L_SZ 7
#define E_SZ 512   // 2H

typedef float f32x4 __attribute__((ext_vector_type(4)));
typedef short bf16x8 __attribute__((ext_vector_type(8)));

__device__ __forceinline__ unsigned short f2bf(float f) {
    union { float f; unsigned u; } v; v.f = f;
    unsigned r = v.u + 0x7FFFu + ((v.u >> 16) & 1u);
    return (unsigned short)(r >> 16);
}
__device__ __forceinline__ float bf2f(unsigned short h) {
    union { unsigned u; float f; } v; v.u = ((unsigned)h) << 16;
    return v.f;
}
__device__ __forceinline__ float fsigm(float x) {
    return __fdividef(1.0f, 1.0f + __expf(-x));
}
__device__ __forceinline__ float ftanh(float x) {
    x = fminf(fmaxf(x, -20.0f), 20.0f);
    float e = __expf(2.0f * x);
    return __fdividef(e - 1.0f, e + 1.0f);
}
__device__ __forceinline__ unsigned char f2fp8(float v) {
    int p = __builtin_amdgcn_cvt_pk_fp8_f32(v, 0.f, 0, false);
    return (unsigned char)(p & 0xff);
}

// ---------------------------------------------------------------------------
// Weight prep into fp8 per-wave VGPR-fragment order:
// Wt idx = (((dw*12 + kk)*4 + hi)*128 + (f*16+u))*8 + e,  dw = dir*8 + wv
// f = q*4+g ; cell j = wv*32 + q*16 + u ; orig row = g*256 + j
// k = kk*32 + hi*8 + e ; k<256 -> w_hh[row][k] else w_ih[row][k-256]
// bp[dw*128 + f*16+u] = combined bias (fp32)
// ---------------------------------------------------------------------------
__global__ __launch_bounds__(256) void prep_w(
    const float* __restrict__ w_ih_f, const float* __restrict__ w_hh_f,
    const float* __restrict__ b_f, const float* __restrict__ w_ih_b,
    const float* __restrict__ w_hh_b, const float* __restrict__ b_b,
    unsigned char* __restrict__ Wt, float* __restrict__ bp)
{
    int idx = blockIdx.x * 256 + threadIdx.x;   // exactly 786432 total
    int e  = idx & 7;
    int cu = (idx >> 3) & 127;      // f*16+u
    int hi = (idx >> 10) & 3;
    int rest = idx >> 12;           // dw*12 + kk
    int kk = rest % 12;
    int dw = rest / 12;             // dir*8 + wv
    int wv = dw & 7, dir = dw >> 3;
    int f = cu >> 4, u = cu & 15;
    int q = f >> 2, g = f & 3;
    int j = wv * 32 + q * 16 + u;
    int row = g * H_SZ + j;
    int k = kk * 32 + hi * 8 + e;
    const float* w_ih = dir ? w_ih_b : w_ih_f;
    const float* w_hh = dir ? w_hh_b : w_hh_f;
    float v = (k < H_SZ) ? w_hh[row * H_SZ + k] : w_ih[row * D_SZ + (k - H_SZ)];
    Wt[idx] = f2fp8(v);
    if (kk == 0 && hi == 0 && e == 0)
        bp[dw * 128 + cu] = (dir ? b_b : b_f)[row];
}

__global__ __launch_bounds__(256) void prep_aw(
    const float* __restrict__ aw1, short* __restrict__ aw1b)
{
    int idx = blockIdx.x * 256 + threadIdx.x;
    if (idx < H_SZ * E_SZ) aw1b[idx] = (short)f2bf(aw1[idx]);
}

// x fp32 -> fp8 e4m3, same [B][T][D] layout
__global__ __launch_bounds__(256) void xprep(
    const float* __restrict__ x, unsigned char* __restrict__ xb)
{
    size_t i = ((size_t)blockIdx.x * 256 + threadIdx.x) * 4;
    float4 v = *reinterpret_cast<const float4*>(x + i);
    int p0 = __builtin_amdgcn_cvt_pk_fp8_f32(v.x, v.y, 0, false);
    int p1 = __builtin_amdgcn_cvt_pk_fp8_f32(v.z, v.w, 0, false);
    unsigned w = (unsigned)(p0 & 0xffff) | ((unsigned)p1 << 16);
    *reinterpret_cast<unsigned*>(xb + i) = w;
}

// ---------------------------------------------------------------------------
// Persistent BiLSTM, fp8 weights fully VGPR-resident.
// 64 blocks = 32 batch-tiles(16 rows) x 2 dirs, 512 threads (8 waves, 2/SIMD).
// Wave wv owns 128 gate-cols = cells [wv*32, wv*32+32) x 4 gates.
// Per lane: 96 fp8 frags (192 VGPR), c[2][4], h fp8 in LDS dbuf.
// ---------------------------------------------------------------------------
__global__ __launch_bounds__(512, 2) void recur_kernel(
    const unsigned char* __restrict__ xb, const unsigned char* __restrict__ Wt,
    const float* __restrict__ bp, unsigned short* __restrict__ hb)
{
    const int dir = blockIdx.x & 1;
    const int b0 = (blockIdx.x >> 1) * 16;
    const int wv = threadIdx.x >> 6;
    const int l  = threadIdx.x & 63;
    const int u = l & 15, hi = l >> 4;

    __shared__ unsigned char hs[2][16][264];   // 264 = 33*8 -> conflict-free b64 reads
    __shared__ unsigned char xs[16][136];      // 136 = 17*8

    // zero hs[0] (h at t=-1)
    for (int i = threadIdx.x; i < 16 * 264 * 1 / 4; i += 512)
        reinterpret_cast<unsigned*>(&hs[0][0][0])[i] = 0u;

    // resident fp8 weights: 96 frags/lane = 192 VGPR
    const unsigned char* wb = Wt + (size_t)(dir * 8 + wv) * 49152 + hi * 1024 + u * 8;
    long wreg[12][8];
    #pragma unroll
    for (int kk = 0; kk < 12; ++kk)
        #pragma unroll
        for (int f = 0; f < 8; ++f)
            wreg[kk][f] = *reinterpret_cast<const long*>(wb + kk * 4096 + f * 128);

    float bias[8];
    #pragma unroll
    for (int f = 0; f < 8; ++f)
        bias[f] = bp[(dir * 8 + wv) * 128 + f * 16 + u];

    // x staging: thread covers (xrow, 4 bytes)
    const int xrow = threadIdx.x >> 5;
    const int xc = (threadIdx.x & 31) * 4;
    const unsigned char* xp = xb + ((size_t)(b0 + xrow) * T_SZ + (dir ? T_SZ - 1 : 0)) * D_SZ + xc;
    const int xstep = dir ? -D_SZ : D_SZ;
    unsigned xreg = *reinterpret_cast<const unsigned*>(xp);

    float c[2][4] = {};
    int cur = 0;

    for (int s = 0; s < T_SZ; ++s) {
        const int t = dir ? (T_SZ - 1 - s) : s;

        __syncthreads();   // prev MFMA xs reads done; hs zero/init visible
        *reinterpret_cast<unsigned*>(&xs[xrow][xc]) = xreg;
        if (s + 1 < T_SZ) { xp += xstep; xreg = *reinterpret_cast<const unsigned*>(xp); }
        __syncthreads();   // xs + prev h visible

        f32x4 acc[8];
        #pragma unroll
        for (int f = 0; f < 8; ++f)
            acc[f] = (f32x4){bias[f], bias[f], bias[f], bias[f]};

        #pragma unroll
        for (int kk = 0; kk < 12; ++kk) {
            long a = (kk < 8)
                ? *reinterpret_cast<const long*>(&hs[cur][u][kk * 32 + hi * 8])
                : *reinterpret_cast<const long*>(&xs[u][(kk - 8) * 32 + hi * 8]);
            #pragma unroll
            for (int f = 0; f < 8; ++f)
                acc[f] = __builtin_amdgcn_mfma_f32_16x16x32_fp8_fp8(a, wreg[kk][f], acc[f], 0, 0, 0);
        }

        // epilogue: lane -> rows hi*4+r, cells j = wv*32 + q*16 + u
        #pragma unroll
        for (int q = 0; q < 2; ++q) {
            const int j = wv * 32 + q * 16 + u;
            #pragma unroll
            for (int r = 0; r < 4; ++r) {
                float iv = fsigm(acc[q * 4 + 0][r]);
                float fv = fsigm(acc[q * 4 + 1][r]);
                float gv = ftanh(acc[q * 4 + 2][r]);
                float ov = fsigm(acc[q * 4 + 3][r]);
                float cn = fv * c[q][r] + iv * gv;
                c[q][r] = cn;
                float h = ov * ftanh(cn);
                int row = hi * 4 + r;
                hs[cur ^ 1][row][j] = f2fp8(h);
                hb[((size_t)t * B_SZ + b0 + row) * E_SZ + dir * H_SZ + j] = f2bf(h);
            }
        }
        cur ^= 1;
    }
}

// ---------------------------------------------------------------------------
// Attention MLP scores, bf16 MFMA (unchanged, passing)
// ---------------------------------------------------------------------------
__global__ __launch_bounds__(256) void attn_mfma(
    const unsigned short* __restrict__ hb, const short* __restrict__ aw1b,
    const float* __restrict__ ab1, const float* __restrict__ aw2,
    float* __restrict__ scores)
{
    const int mt = blockIdx.x >> 1, nt = blockIdx.x & 1;
    const int r0 = mt * 128, n0 = nt * 128;
    const int tid = threadIdx.x;
    const int wv = tid >> 6, l = tid & 63, u = l & 15, hi = l >> 4;
    const int mw = wv >> 1, nw = wv & 1;

    __shared__ unsigned short As[128][40];
    __shared__ unsigned short Bs[128][40];

    f32x4 acc[4][4];
    #pragma unroll
    for (int m = 0; m < 4; ++m)
        #pragma unroll
        for (int n = 0; n < 4; ++n)
            acc[m][n] = (f32x4){0.f, 0.f, 0.f, 0.f};

    const int srow = tid >> 1;
    const int sc0 = (tid & 1) * 16;

    for (int k0 = 0; k0 < E_SZ; k0 += 32) {
        bf16x8 va0 = *reinterpret_cast<const bf16x8*>(hb + (size_t)(r0 + srow) * E_SZ + k0 + sc0);
        bf16x8 va1 = *reinterpret_cast<const bf16x8*>(hb + (size_t)(r0 + srow) * E_SZ + k0 + sc0 + 8);
        bf16x8 vb0 = *reinterpret_cast<const bf16x8*>(aw1b + (size_t)(n0 + srow) * E_SZ + k0 + sc0);
        bf16x8 vb1 = *reinterpret_cast<const bf16x8*>(aw1b + (size_t)(n0 + srow) * E_SZ + k0 + sc0 + 8);
        __syncthreads();
        *reinterpret_cast<bf16x8*>(&As[srow][sc0])     = va0;
        *reinterpret_cast<bf16x8*>(&As[srow][sc0 + 8]) = va1;
        *reinterpret_cast<bf16x8*>(&Bs[srow][sc0])     = vb0;
        *reinterpret_cast<bf16x8*>(&Bs[srow][sc0 + 8]) = vb1;
        __syncthreads();

        bf16x8 af[4], bf[4];
        #pragma unroll
        for (int m = 0; m < 4; ++m)
            af[m] = *reinterpret_cast<const bf16x8*>(&As[mw * 64 + m * 16 + u][hi * 8]);
        #pragma unroll
        for (int n = 0; n < 4; ++n)
            bf[n] = *reinterpret_cast<const bf16x8*>(&Bs[nw * 64 + n * 16 + u][hi * 8]);
        #pragma unroll
        for (int m = 0; m < 4; ++m)
            #pragma unroll
            for (int n = 0; n < 4; ++n)
                acc[m][n] = __builtin_amdgcn_mfma_f32_16x16x32_bf16(af[m], bf[n], acc[m][n], 0, 0, 0);
    }

    float t1[4], t2[4];
    #pragma unroll
    for (int n = 0; n < 4; ++n) {
        int h = n0 + nw * 64 + n * 16 + u;
        t1[n] = ab1[h]; t2[n] = aw2[h];
    }
    #pragma unroll
    for (int m = 0; m < 4; ++m) {
        #pragma unroll
        for (int r = 0; r < 4; ++r) {
            float s = 0.f;
            #pragma unroll
            for (int n = 0; n < 4; ++n)
                s += tanhf(acc[m][n][r] + t1[n]) * t2[n];
            #pragma unroll
            for (int o = 1; o < 16; o <<= 1) s += __shfl_xor(s, o);
            if (u == 0)
                atomicAdd(&scores[r0 + mw * 64 + m * 16 + hi * 4 + r], s);
        }
    }
}

// ---------------------------------------------------------------------------
// Per-batch softmax over T + pooling -> features[b][512]
// ---------------------------------------------------------------------------
__global__ __launch_bounds__(256) void attn_pool(
    const float* __restrict__ scores, const unsigned short* __restrict__ hb,
    float* __restrict__ features)
{
    int b = blockIdx.x;
    int tid = threadIdx.x;
    __shared__ float w[T_SZ];
    __shared__ float smax[4], ssum[4];

    float sc = (tid < T_SZ) ? scores[(size_t)tid * B_SZ + b] : -INFINITY;
    float m = sc;
    for (int o = 32; o; o >>= 1) m = fmaxf(m, __shfl_xor(m, o));
    if ((tid & 63) == 0) smax[tid >> 6] = m;
    __syncthreads();
    float M = fmaxf(fmaxf(smax[0], smax[1]), fmaxf(smax[2], smax[3]));
    float e = (tid < T_SZ) ? expf(sc - M) : 0.f;
    float se = e;
    for (int o = 32; o; o >>= 1) se += __shfl_xor(se, o);
    if ((tid & 63) == 0) ssum[tid >> 6] = se;
    __syncthreads();
    float S = ssum[0] + ssum[1] + ssum[2] + ssum[3];
    if (tid < T_SZ) w[tid] = e / S;
    __syncthreads();

    for (int e0 = tid; e0 < E_SZ; e0 += 256) {
        float acc = 0.f;
        for (int t = 0; t < T_SZ; ++t)
            acc += w[t] * bf2f(hb[((size_t)t * B_SZ + b) * E_SZ + e0]);
        features[(size_t)b * E_SZ + e0] = acc;
    }
}

// ---------------------------------------------------------------------------
// FC: 64 blocks x 8 batch rows
// ---------------------------------------------------------------------------
__global__ __launch_bounds__(256) void fc_kernel(
    const float* __restrict__ features, const float* __restrict__ fc_w,
    const float* __restrict__ fc_b, float* __restrict__ logits)
{
    int bb = blockIdx.x * 8;
    int tid = threadIdx.x;
    __shared__ float f[8][E_SZ];
    for (int i = tid; i < 8 * E_SZ; i += 256)
        f[i >> 9][i & 511] = features[(size_t)(bb + (i >> 9)) * E_SZ + (i & 511)];
    __syncthreads();
    for (int o = tid; o < K_SZ * L_SZ; o += 256) {
        const float* wr = fc_w + (size_t)o * E_SZ;
        float acc[8];
        float bv = fc_b[o];
        #pragma unroll
        for (int b = 0; b < 8; ++b) acc[b] = bv;
        for (int e0 = 0; e0 < E_SZ; ++e0) {
            float wv = wr[e0];
            #pragma unroll
            for (int b = 0; b < 8; ++b) acc[b] += f[b][e0] * wv;
        }
        #pragma unroll
        for (int b = 0; b < 8; ++b)
            logits[(size_t)(bb + b) * (K_SZ * L_SZ) + o] = acc[b];
    }
}

// ---------------------------------------------------------------------------
// CRF loss per batch element
// ---------------------------------------------------------------------------
__global__ __launch_bounds__(64) void crf_kernel(
    const float* __restrict__ logits, const int* __restrict__ labels,
    const float* __restrict__ start_t, const float* __restrict__ trans,
    const float* __restrict__ end_t, float* __restrict__ per_loss)
{
    int b = blockIdx.x;
    int tid = threadIdx.x;
    __shared__ float tr[K_SZ * K_SZ];
    __shared__ float em[K_SZ * L_SZ];
    __shared__ float alpha[K_SZ];

    for (int i = tid; i < K_SZ * K_SZ; i += 64) tr[i] = trans[i];
    for (int i = tid; i < K_SZ * L_SZ; i += 64)
        em[i] = logits[(size_t)b * (K_SZ * L_SZ) + i];
    __syncthreads();
    if (tid < K_SZ) alpha[tid] = start_t[tid] + em[tid];
    __syncthreads();

    for (int t = 1; t < L_SZ; ++t) {
        float na = 0.f;
        if (tid < K_SZ) {
            float m = -INFINITY;
            for (int k = 0; k < K_SZ; ++k)
                m = fmaxf(m, alpha[k] + tr[k * K_SZ + tid]);
            float s = 0.f;
            for (int k = 0; k < K_SZ; ++k)
                s += expf(alpha[k] + tr[k * K_SZ + tid] - m);
            na = m + logf(s) + em[t * K_SZ + tid];
        }
        __syncthreads();
        if (tid < K_SZ) alpha[tid] = na;
        __syncthreads();
    }

    float v = (tid < K_SZ) ? alpha[tid] + end_t[tid] : -INFINITY;
    float m = v;
    for (int o = 32; o; o >>= 1) m = fmaxf(m, __shfl_xor(m, o));
    float e = (tid < K_SZ) ? expf(v - m) : 0.f;
    for (int o = 32; o; o >>= 1) e += __shfl_xor(e, o);
    float logZ = m + logf(e);

    if (tid == 0) {
        const int* lab = labels + (size_t)b * L_SZ;
        float score = start_t[lab[0]] + end_t[lab[L_SZ - 1]];
        for (int t = 0; t < L_SZ; ++t) score += em[t * K_SZ + lab[t]];
        for (int t = 0; t < L_SZ - 1; ++t) score += tr[lab[t] * K_SZ + lab[t + 1]];
        per_loss[b] = logZ - score;
    }
}

__global__ __launch_bounds__(256) void reduce_kernel(
    const float* __restrict__ per_loss, float* __restrict__ out)
{
    int tid = threadIdx.x;
    float s = per_loss[tid] + per_loss[tid + 256];
    for (int o = 32; o; o >>= 1) s += __shfl_xor(s, o);
    __shared__ float part[4];
    if ((tid & 63) == 0) part[tid >> 6] = s;
    __syncthreads();
    if (tid == 0) out[0] = (part[0] + part[1] + part[2] + part[3]) / (float)B_SZ;
}

// ---------------------------------------------------------------------------
extern "C" void kernel_launch(void* const* d_in, const int* in_sizes, int n_in,
                              void* d_out, int out_size, void* d_ws, size_t ws_size,
                              hipStream_t stream)
{
    const float* x      = (const float*)d_in[0];
    const int*   labels = (const int*)d_in[1];
    const float* w_ih_f = (const float*)d_in[2];
    const float* w_hh_f = (const float*)d_in[3];
    const float* b_f    = (const float*)d_in[4];
    const float* w_ih_b = (const float*)d_in[5];
    const float* w_hh_b = (const float*)d_in[6];
    const float* b_b    = (const float*)d_in[7];
    const float* aw1    = (const float*)d_in[8];
    const float* ab1    = (const float*)d_in[9];
    const float* aw2    = (const float*)d_in[10];
    // d_in[11] = ab2 : softmax-invariant, unused
    const float* fc_w   = (const float*)d_in[12];
    const float* fc_b   = (const float*)d_in[13];
    const float* start_t = (const float*)d_in[14];
    const float* trans   = (const float*)d_in[15];
    const float* end_t   = (const float*)d_in[16];
    float* out = (float*)d_out;

    char* ws = (char*)d_ws;
    size_t off = 0;
    unsigned char* Wt = (unsigned char*)(ws + off); off += (size_t)786432;            // fp8 weights
    float* bp        = (float*)(ws + off); off += (size_t)16 * 128 * 4;               // 8KB
    short* aw1b      = (short*)(ws + off); off += (size_t)H_SZ * E_SZ * 2;            // 256KB
    unsigned char* xb = (unsigned char*)(ws + off); off += (size_t)B_SZ * T_SZ * D_SZ; // 8.4MB fp8
    unsigned short* hb = (unsigned short*)(ws + off); off += (size_t)T_SZ * B_SZ * E_SZ * 2; // 67MB
    float* scores    = (float*)(ws + off); off += (size_t)T_SZ * B_SZ * 4;
    float* features  = (float*)(ws + off); off += (size_t)B_SZ * E_SZ * 4;
    float* logits    = (float*)(ws + off); off += (size_t)B_SZ * K_SZ * L_SZ * 4;
    float* per_loss  = (float*)(ws + off); off += (size_t)B_SZ * 4;

    // 1. weight/bias/x prep
    prep_w<<<3072, 256, 0, stream>>>(
        w_ih_f, w_hh_f, b_f, w_ih_b, w_hh_b, b_b, Wt, bp);
    prep_aw<<<(H_SZ * E_SZ + 255) / 256, 256, 0, stream>>>(aw1, aw1b);
    xprep<<<(B_SZ * T_SZ * D_SZ / 4 + 255) / 256, 256, 0, stream>>>(x, xb);

    // 2. zero score accumulator
    hipMemsetAsync(scores, 0, (size_t)T_SZ * B_SZ * 4, stream);

    // 3. BiLSTM — persistent, fp8 weights VGPR-resident
    recur_kernel<<<64, 512, 0, stream>>>(xb, Wt, bp, hb);

    // 4. attention MLP scores (bf16 MFMA)
    attn_mfma<<<1024, 256, 0, stream>>>(hb, aw1b, ab1, aw2, scores);

    // 5. softmax + pooling
    attn_pool<<<B_SZ, 256, 0, stream>>>(scores, hb, features);

    // 6. FC to emissions
    fc_kernel<<<64, 256, 0, stream>>>(features, fc_w, fc_b, logits);

    // 7. CRF loss
    crf_kernel<<<B_SZ, 64, 0, stream>>>(logits, labels, start_t, trans, end_t, per_loss);

    // 8. mean
    reduce_kernel<<<1, 256, 0, stream>>>(per_loss, out);
}